// Round 2
// baseline (104.144 us; speedup 1.0000x reference)
//
#include <hip/hip_runtime.h>

typedef _Float16 half8 __attribute__((ext_vector_type(8)));
typedef float f32x4 __attribute__((ext_vector_type(4)));
typedef float f4 __attribute__((ext_vector_type(4)));

#define P_DIM 1024
#define BM 64
#define NCH 16   // K chunks of 64

// Pack [W_w (48 rows); G_w (8 rows); zeros (8 rows)] as f16 [64][1024] row-major,
// plus combined bias [64] (W_b, G_b, zeros) into workspace.
__global__ __launch_bounds__(256) void prep_weights(
    const float* __restrict__ Gw, const float* __restrict__ Gb,
    const float* __restrict__ Ww, const float* __restrict__ Wb,
    _Float16* __restrict__ Wf, float* __restrict__ biasC) {
  int i = blockIdx.x * 256 + threadIdx.x;   // 0 .. 64*1024-1
  int r = i >> 10, c = i & 1023;
  float v = 0.0f;
  if (r < 48) v = Ww[r * P_DIM + c];
  else if (r < 56) v = Gw[(r - 48) * P_DIM + c];
  Wf[i] = (_Float16)v;
  if (i < 64) {
    float bv = 0.0f;
    if (i < 48) bv = Wb[i];
    else if (i < 56) bv = Gb[i - 48];
    biasC[i] = bv;
  }
}

// Per chunk c (K=64): A-fragments straight from global (no LDS staging — each x
// element is used by exactly one lane), cvt f32->f16 in regs, B from L2.
// A prefetch depth 2 (aA/aB ping-pong), B depth 1 (bA/bB). No main-loop barriers.
#define LOAD_A(dst, c) do { const f4* p_ = xb + (c) * 16; \
    dst[0] = p_[0]; dst[1] = p_[1]; dst[2] = p_[8]; dst[3] = p_[9]; } while (0)

#define LOAD_B(dst, c) do { const _Float16* wp_ = wbase + (c) * 64; \
    dst[0] = *(const half8*)(wp_);                 dst[1] = *(const half8*)(wp_ + 32); \
    dst[2] = *(const half8*)(wp_ + 16 * P_DIM);    dst[3] = *(const half8*)(wp_ + 16 * P_DIM + 32); \
    dst[4] = *(const half8*)(wp_ + 32 * P_DIM);    dst[5] = *(const half8*)(wp_ + 32 * P_DIM + 32); \
    dst[6] = *(const half8*)(wp_ + 48 * P_DIM);    dst[7] = *(const half8*)(wp_ + 48 * P_DIM + 32); \
  } while (0)

// Consume aX (cvt to f16), issue next B (cB) and next A (cA), then MFMA with bX.
// Loads are issued BEFORE the MFMA cluster so the compiler emits counted vmcnt
// (waiting on bX must not drain the freshly issued HBM loads).
#define BODY(aX, bX, bY, cB, cA) do { \
    half8 h0_, h1_; \
    h0_[0]=(_Float16)aX[0][0]; h0_[1]=(_Float16)aX[0][1]; h0_[2]=(_Float16)aX[0][2]; h0_[3]=(_Float16)aX[0][3]; \
    h0_[4]=(_Float16)aX[1][0]; h0_[5]=(_Float16)aX[1][1]; h0_[6]=(_Float16)aX[1][2]; h0_[7]=(_Float16)aX[1][3]; \
    h1_[0]=(_Float16)aX[2][0]; h1_[1]=(_Float16)aX[2][1]; h1_[2]=(_Float16)aX[2][2]; h1_[3]=(_Float16)aX[2][3]; \
    h1_[4]=(_Float16)aX[3][0]; h1_[5]=(_Float16)aX[3][1]; h1_[6]=(_Float16)aX[3][2]; h1_[7]=(_Float16)aX[3][3]; \
    LOAD_B(bY, cB); \
    LOAD_A(aX, cA); \
    acc[0] = __builtin_amdgcn_mfma_f32_16x16x32_f16(h0_, bX[0], acc[0], 0, 0, 0); \
    acc[0] = __builtin_amdgcn_mfma_f32_16x16x32_f16(h1_, bX[1], acc[0], 0, 0, 0); \
    acc[1] = __builtin_amdgcn_mfma_f32_16x16x32_f16(h0_, bX[2], acc[1], 0, 0, 0); \
    acc[1] = __builtin_amdgcn_mfma_f32_16x16x32_f16(h1_, bX[3], acc[1], 0, 0, 0); \
    acc[2] = __builtin_amdgcn_mfma_f32_16x16x32_f16(h0_, bX[4], acc[2], 0, 0, 0); \
    acc[2] = __builtin_amdgcn_mfma_f32_16x16x32_f16(h1_, bX[5], acc[2], 0, 0, 0); \
    acc[3] = __builtin_amdgcn_mfma_f32_16x16x32_f16(h0_, bX[6], acc[3], 0, 0, 0); \
    acc[3] = __builtin_amdgcn_mfma_f32_16x16x32_f16(h1_, bX[7], acc[3], 0, 0, 0); \
  } while (0)

__global__ __launch_bounds__(256, 3) void fused_gate(
    const float* __restrict__ x, const _Float16* __restrict__ Wf,
    const float* __restrict__ biasC, float* __restrict__ out) {
  __shared__ float S[BM][65];   // pre-activations, padded stride (bank-spread)

  const int tid  = threadIdx.x;
  const int lane = tid & 63;
  const int wm   = tid >> 6;        // wave id -> m-tile (16 rows)
  const int row0 = blockIdx.x * BM;
  const int l15  = lane & 15;
  const int lo8  = (lane >> 4) * 8; // k-octet offset of this lane's fragment

  // A: lane l -> row (l&15) of this wave's m-tile, k-octet (l>>4)*8 (f4-aligned)
  const f4* xb = (const f4*)(x + (size_t)(row0 + wm * 16 + l15) * P_DIM + lo8);
  // B: lane l -> output col (l&15), same k-octet mapping
  const _Float16* wbase = Wf + l15 * P_DIM + lo8;

  f32x4 acc[4];
#pragma unroll
  for (int t = 0; t < 4; ++t) acc[t] = (f32x4){0.f, 0.f, 0.f, 0.f};

  f4 aA[4], aB[4];
  half8 bA[8], bB[8];

  LOAD_A(aA, 0);
  LOAD_B(bA, 0);
  LOAD_A(aB, 1);

  for (int c = 0; c < NCH; c += 2) {
    const int cA1 = (c + 2 < NCH) ? c + 2 : NCH - 1;   // aA reload (dup at tail, L2-hit)
    BODY(aA, bA, bB, c + 1, cA1);                      // c+1 <= 15 always
    const int cB2 = (c + 2 < NCH) ? c + 2 : NCH - 1;
    const int cA2 = (c + 3 < NCH) ? c + 3 : NCH - 1;
    BODY(aB, bB, bA, cB2, cA2);
  }

  // acc -> LDS with bias. D layout: col = lane&15, row = (lane>>4)*4 + reg.
#pragma unroll
  for (int t = 0; t < 4; ++t) {
    float bias = biasC[16 * t + l15];
#pragma unroll
    for (int rr = 0; rr < 4; ++rr) {
      S[wm * 16 + (lane >> 4) * 4 + rr][16 * t + l15] = acc[t][rr] + bias;
    }
  }
  __syncthreads();

  // Epilogue: 4 threads per row; thread handles experts [sub*16, sub*16+16).
  const int r2  = tid >> 2;
  const int sub = tid & 3;

  float lg[8];
#pragma unroll
  for (int k = 0; k < 8; ++k) lg[k] = S[r2][48 + k];
  float mx = lg[0];
#pragma unroll
  for (int k = 1; k < 8; ++k) mx = fmaxf(mx, lg[k]);
  float w[8];
  float ssum = 0.f;
#pragma unroll
  for (int k = 0; k < 8; ++k) { w[k] = expf(lg[k] - mx); ssum += w[k]; }
  const float inv = 1.0f / ssum;

  float mix[16];
#pragma unroll
  for (int i = 0; i < 16; ++i) mix[i] = 0.f;

#pragma unroll
  for (int k = 0; k < 8; ++k) {
    float z[6];
#pragma unroll
    for (int j = 0; j < 6; ++j) {
      float tt = S[r2][k * 6 + j];
      float tc = fminf(fmaxf(tt, -0.25f), 0.25f);
      // smooth_step: -16 tc^3 + 3 tc + 0.5
      z[j] = fmaf(tc, fmaf(-16.0f * tc, tc, 3.0f), 0.5f);
    }
    // bits 4,5 of expert index fixed by sub
    float f4v = (sub & 1) ? z[4] : 1.0f - z[4];
    float f5v = (sub & 2) ? z[5] : 1.0f - z[5];
    float wf = w[k] * inv * f4v * f5v;
    // product tree over bits 0..3, all static indices
    float t2[2], t4[4], t8[8], t16[16];
    t2[0] = 1.0f - z[0]; t2[1] = z[0];
#pragma unroll
    for (int i = 0; i < 2; ++i) { t4[i] = t2[i] * (1.0f - z[1]); t4[i + 2] = t2[i] * z[1]; }
#pragma unroll
    for (int i = 0; i < 4; ++i) { t8[i] = t4[i] * (1.0f - z[2]); t8[i + 4] = t4[i] * z[2]; }
#pragma unroll
    for (int i = 0; i < 8; ++i) { t16[i] = t8[i] * (1.0f - z[3]); t16[i + 8] = t8[i] * z[3]; }
#pragma unroll
    for (int i = 0; i < 16; ++i) mix[i] = fmaf(wf, t16[i], mix[i]);
  }

  float* op = out + (size_t)(row0 + r2) * 64 + sub * 16;
#pragma unroll
  for (int g = 0; g < 4; ++g) {
    float4 o;
    o.x = mix[4 * g + 0]; o.y = mix[4 * g + 1];
    o.z = mix[4 * g + 2]; o.w = mix[4 * g + 3];
    ((float4*)op)[g] = o;
  }
}

extern "C" void kernel_launch(void* const* d_in, const int* in_sizes, int n_in,
                              void* d_out, int out_size, void* d_ws, size_t ws_size,
                              hipStream_t stream) {
  const float* x  = (const float*)d_in[0];
  const float* Gw = (const float*)d_in[1];
  const float* Gb = (const float*)d_in[2];
  const float* Ww = (const float*)d_in[3];
  const float* Wb = (const float*)d_in[4];
  float* out = (float*)d_out;

  // workspace: 64*1024 f16 weights (128 KB) + 64 f32 bias
  _Float16* Wf   = (_Float16*)d_ws;
  float*    bias = (float*)((char*)d_ws + 64 * P_DIM * sizeof(_Float16));

  const int B = in_sizes[0] / P_DIM;

  prep_weights<<<dim3(256), dim3(256), 0, stream>>>(Gw, Gb, Ww, Wb, Wf, bias);
  fused_gate<<<dim3(B / BM), dim3(256), 0, stream>>>(x, Wf, bias, out);
  (void)n_in; (void)out_size; (void)ws_size;
}

// Round 5
// 95.324 us; speedup vs baseline: 1.0925x; 1.0925x over previous
//
#include <hip/hip_runtime.h>

typedef _Float16 half8 __attribute__((ext_vector_type(8)));
typedef float f32x4 __attribute__((ext_vector_type(4)));
typedef float f4 __attribute__((ext_vector_type(4)));

#define P_DIM 1024
#define BM 64
#define NH 8          // half-stages of K=128 floats each
#define AF_ROW 132    // LDS A row: 128 floats + 4 pad = 528 B (16B-aligned, bank-rotating)

// Round-2 proven prep: row-major f16 [64][1024] = [W_w(48); G_w(8); 0(8)] + bias[64].
__global__ __launch_bounds__(256) void prep_weights(
    const float* __restrict__ Gw, const float* __restrict__ Gb,
    const float* __restrict__ Ww, const float* __restrict__ Wb,
    _Float16* __restrict__ Wf, float* __restrict__ biasC) {
  int i = blockIdx.x * 256 + threadIdx.x;   // 0 .. 64*1024-1
  int r = i >> 10, c = i & 1023;
  float v = 0.0f;
  if (r < 48) v = Ww[r * P_DIM + c];
  else if (r < 56) v = Gw[(r - 48) * P_DIM + c];
  Wf[i] = (_Float16)v;
  if (i < 64) {
    float bv = 0.0f;
    if (i < 48) bv = Wb[i];
    else if (i < 56) bv = Gb[i - 48];
    biasC[i] = bv;
  }
}

// Round-2 proven B loader (row-major Wf, L2-resident), global sub-chunk c of K=64.
#define LOAD_B(dst, c) do { const _Float16* wp_ = wbase + (c) * 64; \
    dst[0] = *(const half8*)(wp_);                 dst[1] = *(const half8*)(wp_ + 32); \
    dst[2] = *(const half8*)(wp_ + 16 * P_DIM);    dst[3] = *(const half8*)(wp_ + 16 * P_DIM + 32); \
    dst[4] = *(const half8*)(wp_ + 32 * P_DIM);    dst[5] = *(const half8*)(wp_ + 32 * P_DIM + 32); \
    dst[6] = *(const half8*)(wp_ + 48 * P_DIM);    dst[7] = *(const half8*)(wp_ + 48 * P_DIM + 32); \
  } while (0)

// A-fragment floats from the LDS stage; cc = sub-chunk parity within the
// half-stage (0/1). Byte-identical to round-2's direct-global LOAD_A.
#define LOAD_A_LDS(dst, cc) do { const char* p_ = Abase + (cc) * 256; \
    dst[0] = *(const f4*)(p_);       dst[1] = *(const f4*)(p_ + 16); \
    dst[2] = *(const f4*)(p_ + 128); dst[3] = *(const f4*)(p_ + 144); \
  } while (0)

// Round-2 BODY: cvt f32->f16 (same element order), LOAD_B(next), 8 MFMA.
#define BODY(bX, bY, cB, cc) do { \
    f4 aX[4]; \
    LOAD_A_LDS(aX, cc); \
    half8 h0_, h1_; \
    h0_[0]=(_Float16)aX[0][0]; h0_[1]=(_Float16)aX[0][1]; h0_[2]=(_Float16)aX[0][2]; h0_[3]=(_Float16)aX[0][3]; \
    h0_[4]=(_Float16)aX[1][0]; h0_[5]=(_Float16)aX[1][1]; h0_[6]=(_Float16)aX[1][2]; h0_[7]=(_Float16)aX[1][3]; \
    h1_[0]=(_Float16)aX[2][0]; h1_[1]=(_Float16)aX[2][1]; h1_[2]=(_Float16)aX[2][2]; h1_[3]=(_Float16)aX[2][3]; \
    h1_[4]=(_Float16)aX[3][0]; h1_[5]=(_Float16)aX[3][1]; h1_[6]=(_Float16)aX[3][2]; h1_[7]=(_Float16)aX[3][3]; \
    LOAD_B(bY, cB); \
    acc[0] = __builtin_amdgcn_mfma_f32_16x16x32_f16(h0_, bX[0], acc[0], 0, 0, 0); \
    acc[0] = __builtin_amdgcn_mfma_f32_16x16x32_f16(h1_, bX[1], acc[0], 0, 0, 0); \
    acc[1] = __builtin_amdgcn_mfma_f32_16x16x32_f16(h0_, bX[2], acc[1], 0, 0, 0); \
    acc[1] = __builtin_amdgcn_mfma_f32_16x16x32_f16(h1_, bX[3], acc[1], 0, 0, 0); \
    acc[2] = __builtin_amdgcn_mfma_f32_16x16x32_f16(h0_, bX[4], acc[2], 0, 0, 0); \
    acc[2] = __builtin_amdgcn_mfma_f32_16x16x32_f16(h1_, bX[5], acc[2], 0, 0, 0); \
    acc[3] = __builtin_amdgcn_mfma_f32_16x16x32_f16(h0_, bX[6], acc[3], 0, 0, 0); \
    acc[3] = __builtin_amdgcn_mfma_f32_16x16x32_f16(h1_, bX[7], acc[3], 0, 0, 0); \
  } while (0)

__global__ __launch_bounds__(256, 3) void fused_gate(
    const float* __restrict__ x, const _Float16* __restrict__ Wf,
    const float* __restrict__ biasC, float* __restrict__ out) {
  __shared__ __align__(16) float Af[BM][AF_ROW];  // 33792 B, single-buffered A stage
  __shared__ float S[BM][65];                     // 16640 B epilogue scratch

  const int tid  = threadIdx.x;
  const int lane = tid & 63;
  const int w    = tid >> 6;        // wave id 0..3 -> 16-row m-tile
  const int row0 = blockIdx.x * BM;
  const int l15  = lane & 15;
  const int q    = lane >> 4;

  // A stage global: per (row, half-stage) one dwordx2 per lane = 64 x 8 B
  // CONTIGUOUS (512 B single-page burst).
  const char* xg = (const char*)(x + (size_t)(row0 + w * 16) * P_DIM) + lane * 8;
  // B (round-2 layout): lane -> out-col l15, k-octet q*8
  const _Float16* wbase = Wf + l15 * P_DIM + q * 8;

  // LDS stage addresses (same float type on both sides)
  char* Aw = (char*)&Af[w * 16][0] + lane * 8;                 // + i*528 per row
  const char* Abase = (const char*)&Af[w * 16 + l15][0] + q * 32;

  f32x4 acc[4];
#pragma unroll
  for (int t = 0; t < 4; ++t) acc[t] = (f32x4){0.f, 0.f, 0.f, 0.f};

  float2 pf[16];
#pragma unroll
  for (int i = 0; i < 16; ++i) pf[i] = *(const float2*)(xg + i * 4096);  // half-stage 0

  half8 bA[8], bB[8];
  LOAD_B(bA, 0);

  for (int h = 0; h < NH; ++h) {
    if (h) __syncthreads();          // previous half-stage fully consumed
#pragma unroll
    for (int i = 0; i < 16; ++i)
      *(float2*)(Aw + i * 528) = pf[i];
    __syncthreads();                 // stage visible (intra-wave rows anyway)
    // prefetch next half-stage AFTER the barrier: loads fly during BODY,
    // drained at next top-of-loop barrier
    if (h + 1 < NH) {
#pragma unroll
      for (int i = 0; i < 16; ++i)
        pf[i] = *(const float2*)(xg + i * 4096 + (h + 1) * 512);
    }
    const int c0 = h * 2;
    BODY(bA, bB, c0 + 1, 0);                       // consume chunk c0
    const int cn = (c0 + 2 < 16) ? c0 + 2 : 15;    // tail dup (L2-hit)
    BODY(bB, bA, cn, 1);                           // consume chunk c0+1
  }

  __syncthreads();
  // acc -> S with bias. D layout: col = lane&15, row = (lane>>4)*4 + reg.
#pragma unroll
  for (int t = 0; t < 4; ++t) {
    float bias = biasC[16 * t + l15];
#pragma unroll
    for (int rr = 0; rr < 4; ++rr) {
      S[w * 16 + q * 4 + rr][16 * t + l15] = acc[t][rr] + bias;
    }
  }
  __syncthreads();

  // Epilogue (round-2 verbatim): 4 threads/row, experts [sub*16, sub*16+16)
  const int r2  = tid >> 2;
  const int sub = tid & 3;

  float lg[8];
#pragma unroll
  for (int k = 0; k < 8; ++k) lg[k] = S[r2][48 + k];
  float mx = lg[0];
#pragma unroll
  for (int k = 1; k < 8; ++k) mx = fmaxf(mx, lg[k]);
  float wk[8];
  float ssum = 0.f;
#pragma unroll
  for (int k = 0; k < 8; ++k) { wk[k] = expf(lg[k] - mx); ssum += wk[k]; }
  const float inv = 1.0f / ssum;

  float mix[16];
#pragma unroll
  for (int i = 0; i < 16; ++i) mix[i] = 0.f;

#pragma unroll
  for (int k = 0; k < 8; ++k) {
    float z[6];
#pragma unroll
    for (int j = 0; j < 6; ++j) {
      float tt = S[r2][k * 6 + j];
      float tc = fminf(fmaxf(tt, -0.25f), 0.25f);
      // smooth_step: -16 tc^3 + 3 tc + 0.5
      z[j] = fmaf(tc, fmaf(-16.0f * tc, tc, 3.0f), 0.5f);
    }
    float f4v = (sub & 1) ? z[4] : 1.0f - z[4];
    float f5v = (sub & 2) ? z[5] : 1.0f - z[5];
    float wf = wk[k] * inv * f4v * f5v;
    float t2[2], t4[4], t8[8], t16[16];
    t2[0] = 1.0f - z[0]; t2[1] = z[0];
#pragma unroll
    for (int i = 0; i < 2; ++i) { t4[i] = t2[i] * (1.0f - z[1]); t4[i + 2] = t2[i] * z[1]; }
#pragma unroll
    for (int i = 0; i < 4; ++i) { t8[i] = t4[i] * (1.0f - z[2]); t8[i + 4] = t4[i] * z[2]; }
#pragma unroll
    for (int i = 0; i < 8; ++i) { t16[i] = t8[i] * (1.0f - z[3]); t16[i + 8] = t8[i] * z[3]; }
#pragma unroll
    for (int i = 0; i < 16; ++i) mix[i] = fmaf(wf, t16[i], mix[i]);
  }

  float* op = out + (size_t)(row0 + r2) * 64 + sub * 16;
#pragma unroll
  for (int g = 0; g < 4; ++g) {
    float4 o;
    o.x = mix[4 * g + 0]; o.y = mix[4 * g + 1];
    o.z = mix[4 * g + 2]; o.w = mix[4 * g + 3];
    ((float4*)op)[g] = o;
  }
}

extern "C" void kernel_launch(void* const* d_in, const int* in_sizes, int n_in,
                              void* d_out, int out_size, void* d_ws, size_t ws_size,
                              hipStream_t stream) {
  const float* x  = (const float*)d_in[0];
  const float* Gw = (const float*)d_in[1];
  const float* Gb = (const float*)d_in[2];
  const float* Ww = (const float*)d_in[3];
  const float* Wb = (const float*)d_in[4];
  float* out = (float*)d_out;

  _Float16* Wf   = (_Float16*)d_ws;
  float*    bias = (float*)((char*)d_ws + 64 * P_DIM * sizeof(_Float16));

  const int B = in_sizes[0] / P_DIM;

  prep_weights<<<dim3(256), dim3(256), 0, stream>>>(Gw, Gb, Ww, Wb, Wf, bias);
  fused_gate<<<dim3(B / BM), dim3(256), 0, stream>>>(x, Wf, bias, out);
  (void)n_in; (void)out_size; (void)ws_size;
}

// Round 6
// 64.581 us; speedup vs baseline: 1.6126x; 1.4760x over previous
//
#include <hip/hip_runtime.h>

typedef _Float16 half8 __attribute__((ext_vector_type(8)));
typedef float f32x4 __attribute__((ext_vector_type(4)));
typedef float f4 __attribute__((ext_vector_type(4)));

#define P_DIM 1024
#define BM 64
#define NH 8          // half-stages of K=128 floats each
#define AF_ROW 132    // LDS A row: 128 floats + 4 pad = 528 B (16B-aligned, bank-rotating)

// FRAGMENT-MAJOR weights: every B-frag load = 64 lanes x 16 B contiguous (1 KB).
// Wf2[((S*4 + t)*64 + l)*8 + j] = W[t*16 + (l&15)][S*32 + (l>>4)*8 + j]
// rows 0-47 = W_w, 48-55 = G_w, 56-63 = 0.  S = k-step 0..31, t = n-tile 0..3.
__global__ __launch_bounds__(256) void prep_weights(
    const float* __restrict__ Gw, const float* __restrict__ Gb,
    const float* __restrict__ Ww, const float* __restrict__ Wb,
    _Float16* __restrict__ Wf2, float* __restrict__ biasC) {
  int i = blockIdx.x * 256 + threadIdx.x;   // 0 .. 65535
  int j = i & 7;
  int l = (i >> 3) & 63;
  int t = (i >> 9) & 3;
  int S = i >> 11;
  int row = t * 16 + (l & 15);
  int k   = S * 32 + (l >> 4) * 8 + j;
  float v = 0.0f;
  if (row < 48) v = Ww[row * P_DIM + k];
  else if (row < 56) v = Gw[(row - 48) * P_DIM + k];
  Wf2[i] = (_Float16)v;
  if (i < 64) {
    float bv = 0.0f;
    if (i < 48) bv = Wb[i];
    else if (i < 56) bv = Gb[i - 48];
    biasC[i] = bv;
  }
}

// Fragment-major B loader, chunk c (K=64 => 2 S-steps x 4 n-tiles, 1 KB each).
// dst order matches BODY pairing: [2t] = even S (k base c*64), [2t+1] = odd (+32).
#define LOAD_B(dst, c) do { const char* p_ = bg + (size_t)(c) * 8192; \
    dst[0] = *(const half8*)(p_);          dst[1] = *(const half8*)(p_ + 4096); \
    dst[2] = *(const half8*)(p_ + 1024);   dst[3] = *(const half8*)(p_ + 5120); \
    dst[4] = *(const half8*)(p_ + 2048);   dst[5] = *(const half8*)(p_ + 6144); \
    dst[6] = *(const half8*)(p_ + 3072);   dst[7] = *(const half8*)(p_ + 7168); \
  } while (0)

// A floats from LDS stage (cc = chunk parity in half-stage), cvt, 8 MFMA.
#define BODY(bX, cc) do { \
    f4 aX[4]; \
    { const char* p_ = Abase + (cc) * 256; \
      aX[0] = *(const f4*)(p_);       aX[1] = *(const f4*)(p_ + 16); \
      aX[2] = *(const f4*)(p_ + 128); aX[3] = *(const f4*)(p_ + 144); } \
    half8 h0_, h1_; \
    h0_[0]=(_Float16)aX[0][0]; h0_[1]=(_Float16)aX[0][1]; h0_[2]=(_Float16)aX[0][2]; h0_[3]=(_Float16)aX[0][3]; \
    h0_[4]=(_Float16)aX[1][0]; h0_[5]=(_Float16)aX[1][1]; h0_[6]=(_Float16)aX[1][2]; h0_[7]=(_Float16)aX[1][3]; \
    h1_[0]=(_Float16)aX[2][0]; h1_[1]=(_Float16)aX[2][1]; h1_[2]=(_Float16)aX[2][2]; h1_[3]=(_Float16)aX[2][3]; \
    h1_[4]=(_Float16)aX[3][0]; h1_[5]=(_Float16)aX[3][1]; h1_[6]=(_Float16)aX[3][2]; h1_[7]=(_Float16)aX[3][3]; \
    acc[0] = __builtin_amdgcn_mfma_f32_16x16x32_f16(h0_, bX[0], acc[0], 0, 0, 0); \
    acc[0] = __builtin_amdgcn_mfma_f32_16x16x32_f16(h1_, bX[1], acc[0], 0, 0, 0); \
    acc[1] = __builtin_amdgcn_mfma_f32_16x16x32_f16(h0_, bX[2], acc[1], 0, 0, 0); \
    acc[1] = __builtin_amdgcn_mfma_f32_16x16x32_f16(h1_, bX[3], acc[1], 0, 0, 0); \
    acc[2] = __builtin_amdgcn_mfma_f32_16x16x32_f16(h0_, bX[4], acc[2], 0, 0, 0); \
    acc[2] = __builtin_amdgcn_mfma_f32_16x16x32_f16(h1_, bX[5], acc[2], 0, 0, 0); \
    acc[3] = __builtin_amdgcn_mfma_f32_16x16x32_f16(h0_, bX[6], acc[3], 0, 0, 0); \
    acc[3] = __builtin_amdgcn_mfma_f32_16x16x32_f16(h1_, bX[7], acc[3], 0, 0, 0); \
  } while (0)

__global__ __launch_bounds__(256, 3) void fused_gate(
    const float* __restrict__ x, const _Float16* __restrict__ Wf2,
    const float* __restrict__ biasC, float* __restrict__ out) {
  __shared__ __align__(16) float Af[BM][AF_ROW];  // 33792 B, single-buffered A stage
  __shared__ float S[BM][65];                     // 16640 B epilogue scratch

  const int tid  = threadIdx.x;
  const int lane = tid & 63;
  const int w    = tid >> 6;        // wave id 0..3 -> 16-row m-tile
  const int row0 = blockIdx.x * BM;
  const int l15  = lane & 15;
  const int q    = lane >> 4;

  // A stage global: per (row, half-stage) one dwordx2 per lane = 64 x 8 B
  // CONTIGUOUS (512 B single-page burst).
  const char* xg = (const char*)(x + (size_t)(row0 + w * 16) * P_DIM) + lane * 8;
  // B fragment-major: wave-uniform base + lane*16 (contiguous 1 KB per load)
  const char* bg = (const char*)Wf2 + lane * 16;

  // LDS stage addresses (same float type on both sides)
  char* Aw = (char*)&Af[w * 16][0] + lane * 8;                 // + i*528 per row
  const char* Abase = (const char*)&Af[w * 16 + l15][0] + q * 32;

  f32x4 acc[4];
#pragma unroll
  for (int t = 0; t < 4; ++t) acc[t] = (f32x4){0.f, 0.f, 0.f, 0.f};

  float2 pf[16];
#pragma unroll
  for (int i = 0; i < 16; ++i) pf[i] = *(const float2*)(xg + i * 4096);  // half-stage 0

  half8 bA[8], bB[8];
  LOAD_B(bA, 0);

  for (int h = 0; h < NH; ++h) {
    if (h) __syncthreads();          // previous half-stage fully consumed
#pragma unroll
    for (int i = 0; i < 16; ++i)
      *(float2*)(Aw + i * 528) = pf[i];   // implicit vmcnt(0): all loads drained here
    __syncthreads();                 // stage visible
    const int c0 = h * 2;
    // B for chunk c0+1 FIRST (older in VMEM FIFO than the HBM prefetch below,
    // so BODY(bB)'s wait does NOT drain the prefetch)
    LOAD_B(bB, c0 + 1);
    // next half-stage A prefetch (HBM, youngest; drained at next stage top)
    if (h + 1 < NH) {
#pragma unroll
      for (int i = 0; i < 16; ++i)
        pf[i] = *(const float2*)(xg + i * 4096 + (h + 1) * 512);
    }
    BODY(bA, 0);                     // chunk c0 (bA pre-loaded)
    BODY(bB, 1);                     // chunk c0+1
    if (h + 1 < NH)
      LOAD_B(bA, c0 + 2);            // next even chunk; drains at next stage top
  }

  __syncthreads();
  // acc -> S with bias. D layout: col = lane&15, row = (lane>>4)*4 + reg.
#pragma unroll
  for (int t = 0; t < 4; ++t) {
    float bias = biasC[16 * t + l15];
#pragma unroll
    for (int rr = 0; rr < 4; ++rr) {
      S[w * 16 + q * 4 + rr][16 * t + l15] = acc[t][rr] + bias;
    }
  }
  __syncthreads();

  // Epilogue (round-2 verbatim): 4 threads/row, experts [sub*16, sub*16+16)
  const int r2  = tid >> 2;
  const int sub = tid & 3;

  float lg[8];
#pragma unroll
  for (int k = 0; k < 8; ++k) lg[k] = S[r2][48 + k];
  float mx = lg[0];
#pragma unroll
  for (int k = 1; k < 8; ++k) mx = fmaxf(mx, lg[k]);
  float wk[8];
  float ssum = 0.f;
#pragma unroll
  for (int k = 0; k < 8; ++k) { wk[k] = expf(lg[k] - mx); ssum += wk[k]; }
  const float inv = 1.0f / ssum;

  float mix[16];
#pragma unroll
  for (int i = 0; i < 16; ++i) mix[i] = 0.f;

#pragma unroll
  for (int k = 0; k < 8; ++k) {
    float z[6];
#pragma unroll
    for (int j = 0; j < 6; ++j) {
      float tt = S[r2][k * 6 + j];
      float tc = fminf(fmaxf(tt, -0.25f), 0.25f);
      // smooth_step: -16 tc^3 + 3 tc + 0.5
      z[j] = fmaf(tc, fmaf(-16.0f * tc, tc, 3.0f), 0.5f);
    }
    float f4v = (sub & 1) ? z[4] : 1.0f - z[4];
    float f5v = (sub & 2) ? z[5] : 1.0f - z[5];
    float wf = wk[k] * inv * f4v * f5v;
    float t2[2], t4[4], t8[8], t16[16];
    t2[0] = 1.0f - z[0]; t2[1] = z[0];
#pragma unroll
    for (int i = 0; i < 2; ++i) { t4[i] = t2[i] * (1.0f - z[1]); t4[i + 2] = t2[i] * z[1]; }
#pragma unroll
    for (int i = 0; i < 4; ++i) { t8[i] = t4[i] * (1.0f - z[2]); t8[i + 4] = t4[i] * z[2]; }
#pragma unroll
    for (int i = 0; i < 8; ++i) { t16[i] = t8[i] * (1.0f - z[3]); t16[i + 8] = t8[i] * z[3]; }
#pragma unroll
    for (int i = 0; i < 16; ++i) mix[i] = fmaf(wf, t16[i], mix[i]);
  }

  float* op = out + (size_t)(row0 + r2) * 64 + sub * 16;
#pragma unroll
  for (int g = 0; g < 4; ++g) {
    float4 o;
    o.x = mix[4 * g + 0]; o.y = mix[4 * g + 1];
    o.z = mix[4 * g + 2]; o.w = mix[4 * g + 3];
    ((float4*)op)[g] = o;
  }
}

extern "C" void kernel_launch(void* const* d_in, const int* in_sizes, int n_in,
                              void* d_out, int out_size, void* d_ws, size_t ws_size,
                              hipStream_t stream) {
  const float* x  = (const float*)d_in[0];
  const float* Gw = (const float*)d_in[1];
  const float* Gb = (const float*)d_in[2];
  const float* Ww = (const float*)d_in[3];
  const float* Wb = (const float*)d_in[4];
  float* out = (float*)d_out;

  _Float16* Wf2  = (_Float16*)d_ws;
  float*    bias = (float*)((char*)d_ws + 64 * P_DIM * sizeof(_Float16));

  const int B = in_sizes[0] / P_DIM;

  prep_weights<<<dim3(256), dim3(256), 0, stream>>>(Gw, Gb, Ww, Wb, Wf2, bias);
  fused_gate<<<dim3(B / BM), dim3(256), 0, stream>>>(x, Wf2, bias, out);
  (void)n_in; (void)out_size; (void)ws_size;
}